// Round 12
// baseline (53.763 us; speedup 1.0000x reference)
//
#include <hip/hip_runtime.h>
#include <math.h>

// Problem constants
#define BATCH 64
#define HH 512
#define WW 512
#define PAD 15
#define NELEM ((size_t)BATCH * HH * WW)
#define INV_KK (1.0f / 961.0f)

#define TILE_H 32              // rows per block
#define RPI 8                  // rows per iteration (2 per wave)
#define NIT (TILE_H / RPI)     // 4 iterations
#define BPI (HH / TILE_H)      // 16 blocks per image
#define NBLK (BATCH * BPI)     // 1024 blocks -> 4 blocks/CU
#define NXCD 8

typedef float f4 __attribute__((ext_vector_type(4)));

__device__ __forceinline__ float wave_reduce(float v) {
    #pragma unroll
    for (int off = 32; off; off >>= 1) v += __shfl_down(v, off, 64);
    return v;
}

// ---------------------------------------------------------------------------
// R11 (51.5us) + ILP doubling:
//  - 8 rows/iter, 2 per wave: two INDEPENDENT scan chains interleave (row B's
//    bpermutes execute in row A's latency shadow); 4 barriers/block (was 8).
//  - in-place prefix (P buffer deleted): LDS 32.8KB -> still 4 blocks/CU.
//  - pred-row loads (cold HBM) hoisted BEFORE the scan -> latency hides under
//    the shuffle chain. mask loss-loads stay inline (L2 hits).
//  - R11's mask add/sub register prefetch extended to 8 rows (32 regs).
// Safety of buffer reuse unchanged: a wave reaches iter it+2's producer (same
// buffer as it) only after barrier(it+1), which all waves reach only after
// finishing iter it's loss.
// ---------------------------------------------------------------------------
__global__ __launch_bounds__(256) void fused_kernel(const float* __restrict__ pred,
                                                    const float* __restrict__ mask,
                                                    double* __restrict__ partials) {
    __shared__ float vrow[2][RPI][WW];   // double-buffered; prefix in place
    __shared__ float red[3][4];

    // XCD swizzle: xcd = f%8 (HW round-robin); each XCD owns 8 whole images.
    const int f    = blockIdx.x;
    const int xcd  = f & (NXCD - 1);
    const int slot = f >> 3;               // 0..127
    const int img  = xcd * 8 + (slot >> 4);
    const int tile = slot & (BPI - 1);

    const int tid  = threadIdx.x;
    const int lane = tid & 63;
    const int wv   = tid >> 6;
    const int h0   = tile * TILE_H;        // block's first output row (max 480)
    const int c0   = tid;                  // producer columns
    const int c1   = tid + 256;

    const float* mb = mask + (size_t)img * HH * WW;
    const float* pb = pred + (size_t)img * HH * WW;

    // --- init rolling vertical window for row h0: rows [max(0,h0-15), min(511,h0+15)]
    float r0 = 0.0f, r1 = 0.0f;
    {
        int lo = h0 - PAD; if (lo < 0) lo = 0;
        int hi = h0 + PAD; if (hi > HH - 1) hi = HH - 1;
        for (int y = lo; y <= hi; ++y) {
            r0 += mb[(size_t)y * WW + c0];
            r1 += mb[(size_t)y * WW + c1];
        }
    }

    // Prefetched add/sub rows for the upcoming iteration: for output rows
    // h = hb..hb+7, slide adds row h+16 and subtracts row h-15.
    float pa[RPI], ps[RPI], qa[RPI], qs[RPI];

    #define PREFETCH(ii)                                                   \
    {                                                                      \
        const int hb = h0 + RPI * (ii);                                    \
        _Pragma("unroll")                                                  \
        for (int j = 0; j < RPI; ++j) {                                    \
            const int ar = hb + 16 + j;                                    \
            const int sr = hb - 15 + j;                                    \
            pa[j] = (ar < HH) ? mb[(size_t)ar * WW + c0] : 0.0f;           \
            qa[j] = (ar < HH) ? mb[(size_t)ar * WW + c1] : 0.0f;           \
            ps[j] = (sr >= 0) ? mb[(size_t)sr * WW + c0] : 0.0f;           \
            qs[j] = (sr >= 0) ? mb[(size_t)sr * WW + c1] : 0.0f;           \
        }                                                                  \
    }

    PREFETCH(0)

    float accb = 0.0f, acci = 0.0f, accu = 0.0f;

    #pragma unroll 1   // forbid outer unroll: protects the register budget
    for (int it = 0; it < NIT; ++it) {
        const int hbase = h0 + it * RPI;
        float (*vb)[WW] = vrow[it & 1];

        // --- producer: pure LDS/VALU, consumes prefetched rows ---
        #pragma unroll
        for (int j = 0; j < RPI; ++j) {
            vb[j][c0] = r0;
            vb[j][c1] = r1;
            r0 += pa[j] - ps[j];
            r1 += qa[j] - qs[j];
        }
        __syncthreads();   // vb visible to all waves (the only barrier)

        // --- issue next iteration's mask loads (hide under scan+loss) ---
        if (it + 1 < NIT) PREFETCH(it + 1)

        // --- wave wv owns rows ra=2wv, rb=2wv+1 of this 8-row group ---
        const int ra = 2 * wv;
        const int rbr = ra + 1;
        const int hA = hbase + ra;
        const int hB = hA + 1;
        const size_t rbA = (size_t)hA * WW;
        const size_t rbB = (size_t)hB * WW;

        // --- hoist cold pred loads BEFORE the scan chain ---
        float prA[8], prB[8];
        #pragma unroll
        for (int k = 0; k < 8; ++k) {
            prA[k] = pb[rbA + lane + 64 * k];
            prB[k] = pb[rbB + lane + 64 * k];
        }

        // --- two independent prefix scans, interleaved (in place) ---
        f4 a0 = *(const f4*)&vb[ra][8 * lane];
        f4 a1 = *(const f4*)&vb[ra][8 * lane + 4];
        f4 b0 = *(const f4*)&vb[rbr][8 * lane];
        f4 b1 = *(const f4*)&vb[rbr][8 * lane + 4];
        float A0 = a0.x,      B0 = b0.x;
        float A1 = A0 + a0.y, B1 = B0 + b0.y;
        float A2 = A1 + a0.z, B2 = B1 + b0.z;
        float A3 = A2 + a0.w, B3 = B2 + b0.w;
        float A4 = A3 + a1.x, B4 = B3 + b1.x;
        float A5 = A4 + a1.y, B5 = B4 + b1.y;
        float A6 = A5 + a1.z, B6 = B5 + b1.z;
        float A7 = A6 + a1.w, B7 = B6 + b1.w;
        float inclA = A7, inclB = B7;
        #pragma unroll
        for (int off = 1; off < 64; off <<= 1) {
            float nA = __shfl_up(inclA, off, 64);
            float nB = __shfl_up(inclB, off, 64);
            if (lane >= off) { inclA += nA; inclB += nB; }
        }
        const float exA = inclA - A7;
        const float exB = inclB - B7;
        f4 wa0, wa1, wb0, wb1;
        wa0.x = exA + A0; wa0.y = exA + A1; wa0.z = exA + A2; wa0.w = exA + A3;
        wa1.x = exA + A4; wa1.y = exA + A5; wa1.z = exA + A6; wa1.w = exA + A7;
        wb0.x = exB + B0; wb0.y = exB + B1; wb0.z = exB + B2; wb0.w = exB + B3;
        wb1.x = exB + B4; wb1.y = exB + B5; wb1.z = exB + B6; wb1.w = exB + B7;
        *(f4*)&vb[ra][8 * lane]      = wa0;
        *(f4*)&vb[ra][8 * lane + 4]  = wa1;
        *(f4*)&vb[rbr][8 * lane]     = wb0;
        *(f4*)&vb[rbr][8 * lane + 4] = wb1;
        // no barrier: rows ra/rbr are wave-private (same-wave DS ordering).

        // --- loss for both rows; lane owns w = lane + 64k ---
        #pragma unroll
        for (int k = 0; k < 8; ++k) {
            const int w = lane + 64 * k;
            int hiw = w + PAD; if (hiw > WW - 1) hiw = WW - 1;
            const int low = w - PAD - 1;

            float sA = vb[ra][hiw];
            float sB = vb[rbr][hiw];
            if (low >= 0) { sA -= vb[ra][low]; sB -= vb[rbr][low]; }

            {
                const float m  = mb[rbA + w];
                const float pr = prA[k];
                const float weit = 1.0f + 5.0f * fabsf(sA * INV_KK - m);
                const float e    = __expf(-fabsf(pr));
                const float bce  = fmaxf(pr, 0.0f) - pr * m + __logf(1.0f + e);
                const float inv  = __builtin_amdgcn_rcpf(1.0f + e);
                const float p    = (pr >= 0.0f) ? inv : e * inv;
                accb += bce;
                acci += p * m * weit;
                accu += (p + m) * weit;
            }
            {
                const float m  = mb[rbB + w];
                const float pr = prB[k];
                const float weit = 1.0f + 5.0f * fabsf(sB * INV_KK - m);
                const float e    = __expf(-fabsf(pr));
                const float bce  = fmaxf(pr, 0.0f) - pr * m + __logf(1.0f + e);
                const float inv  = __builtin_amdgcn_rcpf(1.0f + e);
                const float p    = (pr >= 0.0f) ? inv : e * inv;
                accb += bce;
                acci += p * m * weit;
                accu += (p + m) * weit;
            }
        }
        // no end barrier: vrow is double-buffered (safety argument above).
    }
    #undef PREFETCH

    // --- block reduction ---
    accb = wave_reduce(accb);
    acci = wave_reduce(acci);
    accu = wave_reduce(accu);
    if (lane == 0) { red[0][wv] = accb; red[1][wv] = acci; red[2][wv] = accu; }
    __syncthreads();
    if (tid == 0) {
        double bt = (double)red[0][0] + red[0][1] + red[0][2] + red[0][3];
        double it2 = (double)red[1][0] + red[1][1] + red[1][2] + red[1][3];
        double ut = (double)red[2][0] + red[2][1] + red[2][2] + red[2][3];
        const size_t pidx = (size_t)img * BPI + tile;   // un-swizzled index
        partials[pidx * 3 + 0] = bt;
        partials[pidx * 3 + 1] = it2;
        partials[pidx * 3 + 2] = ut;
    }
}

// ---------------------------------------------------------------------------
// Finalize from per-block partials (indexed img*BPI + tile), NBLK = 1024.
// ---------------------------------------------------------------------------
__global__ __launch_bounds__(256) void finalize_kernel(const double* __restrict__ partials,
                                                       float* __restrict__ out) {
    __shared__ double redbce[4];
    int tid = threadIdx.x, lane = tid & 63, wv = tid >> 6;

    double bsum = 0.0;
    for (int i = tid; i < NBLK; i += 256) bsum += partials[(size_t)i * 3 + 0];
    #pragma unroll
    for (int off = 32; off; off >>= 1) bsum += __shfl_down(bsum, off, 64);
    if (lane == 0) redbce[wv] = bsum;
    __syncthreads();

    double wiou_term = 0.0;
    if (tid < 64) {
        int bb = tid;
        double it = 0.0, ut = 0.0;
        for (int j = 0; j < BPI; ++j) {
            it += partials[(size_t)(bb * BPI + j) * 3 + 1];
            ut += partials[(size_t)(bb * BPI + j) * 3 + 2];
        }
        wiou_term = 1.0 - (it + 1.0) / (ut - it + 1.0);
    }
    if (wv == 0) {
        #pragma unroll
        for (int off = 32; off; off >>= 1) wiou_term += __shfl_down(wiou_term, off, 64);
    }
    if (tid == 0) {
        double wbce = (redbce[0] + redbce[1] + redbce[2] + redbce[3]) / (double)NELEM;
        out[0] = (float)(wbce + wiou_term * (1.0 / 64.0));
    }
}

// ---------------------------------------------------------------------------
// Fallback path (tiny ws): recompute vertical sums in-kernel + atomics.
// ---------------------------------------------------------------------------
#define ACC_DOUBLES 129
__global__ __launch_bounds__(256) void rowpass_nows_kernel(const float* __restrict__ pred,
                                                           const float* __restrict__ mask,
                                                           double* __restrict__ acc) {
    __shared__ float vrow1[WW];
    __shared__ float red[3][4];
    int b = blockIdx.x / HH;
    int h = blockIdx.x % HH;
    int lo = h - PAD; if (lo < 0) lo = 0;
    int hi = h + PAD; if (hi > HH - 1) hi = HH - 1;
    float s0 = 0.0f, s1 = 0.0f;
    const float* mb = mask + (size_t)b * HH * WW;
    for (int y = lo; y <= hi; ++y) {
        s0 += mb[(size_t)y * WW + threadIdx.x];
        s1 += mb[(size_t)y * WW + threadIdx.x + 256];
    }
    vrow1[threadIdx.x]       = s0;
    vrow1[threadIdx.x + 256] = s1;
    __syncthreads();

    size_t base = ((size_t)b * HH + h) * WW;
    float bce_p = 0.0f, inter_p = 0.0f, uni_p = 0.0f;
    for (int w = threadIdx.x; w < WW; w += 256) {
        int wlo = w - PAD; if (wlo < 0) wlo = 0;
        int whi = w + PAD; if (whi > WW - 1) whi = WW - 1;
        float s = 0.0f;
        for (int k = wlo; k <= whi; ++k) s += vrow1[k];
        float m  = mask[base + w];
        float pr = pred[base + w];
        float weit = 1.0f + 5.0f * fabsf(s * INV_KK - m);
        float e   = expf(-fabsf(pr));
        float bce = fmaxf(pr, 0.0f) - pr * m + log1pf(e);
        float inv = 1.0f / (1.0f + e);
        float p   = (pr >= 0.0f) ? inv : e * inv;
        bce_p += bce; inter_p += p * m * weit; uni_p += (p + m) * weit;
    }
    int lane = threadIdx.x & 63, wvv = threadIdx.x >> 6;
    bce_p = wave_reduce(bce_p); inter_p = wave_reduce(inter_p); uni_p = wave_reduce(uni_p);
    if (lane == 0) { red[0][wvv] = bce_p; red[1][wvv] = inter_p; red[2][wvv] = uni_p; }
    __syncthreads();
    if (threadIdx.x == 0) {
        atomicAdd(&acc[0], (double)(red[0][0] + red[0][1] + red[0][2] + red[0][3]));
        atomicAdd(&acc[1 + b], (double)(red[1][0] + red[1][1] + red[1][2] + red[1][3]));
        atomicAdd(&acc[65 + b], (double)(red[2][0] + red[2][1] + red[2][2] + red[2][3]));
    }
}

__global__ void finalize_atomic_kernel(const double* __restrict__ acc, float* __restrict__ out) {
    int b = threadIdx.x;
    double inter = acc[1 + b];
    double uni   = acc[65 + b];
    double wiou = 1.0 - (inter + 1.0) / (uni - inter + 1.0);
    #pragma unroll
    for (int off = 32; off; off >>= 1) wiou += __shfl_down(wiou, off, 64);
    if (b == 0) {
        double wbce = acc[0] / (double)NELEM;
        out[0] = (float)(wbce + wiou * (1.0 / 64.0));
    }
}

// ---------------------------------------------------------------------------
extern "C" void kernel_launch(void* const* d_in, const int* in_sizes, int n_in,
                              void* d_out, int out_size, void* d_ws, size_t ws_size,
                              hipStream_t stream) {
    const float* pred = (const float*)d_in[0];
    const float* mask = (const float*)d_in[1];
    float* out = (float*)d_out;

    const size_t part_bytes = (size_t)NBLK * 3 * sizeof(double);   // 24 KiB

    if (ws_size >= part_bytes) {
        double* partials = (double*)d_ws;
        fused_kernel<<<NBLK, 256, 0, stream>>>(pred, mask, partials);
        finalize_kernel<<<1, 256, 0, stream>>>(partials, out);
    } else {
        double* acc = (double*)d_ws;
        hipMemsetAsync(acc, 0, ACC_DOUBLES * sizeof(double), stream);
        rowpass_nows_kernel<<<BATCH * HH, 256, 0, stream>>>(pred, mask, acc);
        finalize_atomic_kernel<<<1, 64, 0, stream>>>(acc, out);
    }
}